// Round 1
// baseline (207.470 us; speedup 1.0000x reference)
//
#include <hip/hip_runtime.h>
#include <hip/hip_bf16.h>

// ---------- problem constants ----------
constexpr int Bb   = 2;
constexpr int Ss   = 2048;
constexpr int Dm   = 1024;
constexpr int Hh   = 16;
constexpr int Hd   = 64;
constexpr int Mtot = Bb * Ss;      // 4096

typedef __bf16 bf16x8 __attribute__((ext_vector_type(8)));
typedef float  f32x4  __attribute__((ext_vector_type(4)));
typedef __attribute__((address_space(1))) unsigned int u32_as1;
typedef __attribute__((address_space(3))) unsigned int u32_as3;

__device__ __forceinline__ void gload_lds16(const void* g, void* l) {
  __builtin_amdgcn_global_load_lds((const u32_as1*)g, (u32_as3*)l, 16, 0, 0);
}

__device__ __forceinline__ unsigned short f2bf(float f) {
  union { float f; unsigned u; } x; x.f = f;
  unsigned r = x.u + 0x7fffu + ((x.u >> 16) & 1u);   // RNE
  return (unsigned short)(r >> 16);
}

// ---------- convert x f32 -> bf16 (row-major [M,K]) ----------
__global__ void k_convert_x(const float* __restrict__ in, unsigned short* __restrict__ out) {
  int i = blockIdx.x * blockDim.x + threadIdx.x;        // i < Mtot*Dm/4
  float4 v = ((const float4*)in)[i];
  ushort4 o;
  o.x = f2bf(v.x); o.y = f2bf(v.y); o.z = f2bf(v.z); o.w = f2bf(v.w);
  ((ushort4*)out)[i] = o;
}

// ---------- transpose-convert W [K,N] f32 -> Wt [N,K] bf16 ----------
__global__ void k_transpose_conv(const float* __restrict__ W, unsigned short* __restrict__ Wt,
                                 int K, int N) {
  __shared__ float t[32][33];
  int n0 = blockIdx.x * 32, k0 = blockIdx.y * 32;
  int tx = threadIdx.x, ty = threadIdx.y;
#pragma unroll
  for (int j = 0; j < 32; j += 8)
    t[ty + j][tx] = W[(size_t)(k0 + ty + j) * N + n0 + tx];
  __syncthreads();
#pragma unroll
  for (int j = 0; j < 32; j += 8)
    Wt[(size_t)(n0 + ty + j) * K + k0 + tx] = f2bf(t[tx][ty + j]);
}

// ---------- n projection: invn[b,h,s] = exp(-(x @ Wn + bn)) , all f32 ----------
__global__ void k_n_proj(const float* __restrict__ x, const float* __restrict__ Wn,
                         const float* __restrict__ bn, float* __restrict__ invn) {
  __shared__ float xl[4][1024];
  int tid = threadIdx.x, w = tid >> 6, lane = tid & 63;
  int row = blockIdx.x * 4 + w;                       // [0, 4096)
  const float4* x4 = (const float4*)(x + (size_t)row * Dm);
#pragma unroll
  for (int j = 0; j < 4; ++j)
    *(float4*)&xl[w][(j * 64 + lane) * 4] = x4[j * 64 + lane];
  __syncthreads();
  const float4* Wn4 = (const float4*)Wn;
  f32x4 sum = {0.f, 0.f, 0.f, 0.f};
#pragma unroll 4
  for (int j = 0; j < 64; ++j) {
    float xv = xl[w][j * 16 + (lane >> 2)];
    float4 wv = Wn4[j * 64 + lane];
    sum[0] += xv * wv.x; sum[1] += xv * wv.y; sum[2] += xv * wv.z; sum[3] += xv * wv.w;
  }
#pragma unroll
  for (int m = 4; m < 64; m <<= 1) {
    sum[0] += __shfl_xor(sum[0], m);
    sum[1] += __shfl_xor(sum[1], m);
    sum[2] += __shfl_xor(sum[2], m);
    sum[3] += __shfl_xor(sum[3], m);
  }
  if (lane < 4) {
    int b = row >> 11, s = row & 2047;
#pragma unroll
    for (int e = 0; e < 4; ++e) {
      int h = lane * 4 + e;
      float nv = sum[e] + bn[h];
      invn[((size_t)(b * Hh + h)) * Ss + s] = expf(-nv);
    }
  }
}

// ---------- GEMM: A[M,K] bf16 row-major  x  BT[N,K] bf16  (+bias), epilogue scatter ----------
// MODE 0: N=2048, out0=q [b,h,t,d], out1=k [b,h,t,d]   (bf16)
// MODE 1: N=1024, out0=v [b,h,d,t]                      (bf16, transposed for attn)
// MODE 2: N=1024, out0=final f32 [m,n]
template <int MODE>
__global__ __launch_bounds__(256, 2) void k_gemm_bt(
    const unsigned short* __restrict__ A, const unsigned short* __restrict__ BT,
    const float* __restrict__ bias, void* __restrict__ out0, void* __restrict__ out1,
    int M, int N, int K) {
  __shared__ __align__(16) unsigned short As[128 * 64];
  __shared__ __align__(16) unsigned short Bs[128 * 64];
  int tid = threadIdx.x, w = tid >> 6, lane = tid & 63;
  int m0 = blockIdx.y * 128, n0 = blockIdx.x * 128;
  int wm = w >> 1, wn = w & 1;
  f32x4 acc[4][4] = {};

  for (int kt = 0; kt < (K >> 6); ++kt) {
#pragma unroll
    for (int i = 0; i < 4; ++i) {
      int lin = i * 2048 + w * 512 + lane * 8;
      int r = lin >> 6, c = lin & 63;
      gload_lds16(A + (size_t)(m0 + r) * K + kt * 64 + c, As + i * 2048 + w * 512);
    }
#pragma unroll
    for (int i = 0; i < 4; ++i) {
      int lin = i * 2048 + w * 512 + lane * 8;
      int r = lin >> 6, c = lin & 63;
      gload_lds16(BT + (size_t)(n0 + r) * K + kt * 64 + c, Bs + i * 2048 + w * 512);
    }
    __syncthreads();
#pragma unroll
    for (int ks = 0; ks < 2; ++ks) {
      bf16x8 af[4], bfr[4];
#pragma unroll
      for (int mt = 0; mt < 4; ++mt)
        af[mt] = *(const bf16x8*)(As + (wm * 64 + mt * 16 + (lane & 15)) * 64 + ks * 32 + (lane >> 4) * 8);
#pragma unroll
      for (int nt = 0; nt < 4; ++nt)
        bfr[nt] = *(const bf16x8*)(Bs + (wn * 64 + nt * 16 + (lane & 15)) * 64 + ks * 32 + (lane >> 4) * 8);
#pragma unroll
      for (int mt = 0; mt < 4; ++mt)
#pragma unroll
        for (int nt = 0; nt < 4; ++nt)
          acc[mt][nt] = __builtin_amdgcn_mfma_f32_16x16x32_bf16(af[mt], bfr[nt], acc[mt][nt], 0, 0, 0);
    }
    __syncthreads();
  }

#pragma unroll
  for (int mt = 0; mt < 4; ++mt) {
#pragma unroll
    for (int nt = 0; nt < 4; ++nt) {
      int n = n0 + wn * 64 + nt * 16 + (lane & 15);
      float bb = bias[n];
      if (MODE == 1) {
        int tbase = m0 + wm * 64 + mt * 16 + (lane >> 4) * 4;
        int b = tbase >> 11, t = tbase & 2047;
        int h = n >> 6, d = n & 63;
        ushort4 o;
        o.x = f2bf(acc[mt][nt][0] + bb);
        o.y = f2bf(acc[mt][nt][1] + bb);
        o.z = f2bf(acc[mt][nt][2] + bb);
        o.w = f2bf(acc[mt][nt][3] + bb);
        *(ushort4*)((unsigned short*)out0 + ((size_t)(b * Hh + h) * Hd + d) * Ss + t) = o;
      } else {
#pragma unroll
        for (int r = 0; r < 4; ++r) {
          int m = m0 + wm * 64 + mt * 16 + (lane >> 4) * 4 + r;
          float vv = acc[mt][nt][r] + bb;
          if (MODE == 0) {
            int sel = n >> 10, h = (n >> 6) & 15, d = n & 63, b = m >> 11, t = m & 2047;
            unsigned short* dst = sel ? (unsigned short*)out1 : (unsigned short*)out0;
            dst[(((size_t)(b * Hh + h)) * Ss + t) * Hd + d] = f2bf(vv);
          } else {  // MODE 2
            ((float*)out0)[(size_t)m * N + n] = vv;
          }
        }
      }
    }
  }
}

// ---------- causal linear attention ----------
// q,k: [bh][t][d] bf16 ; v: [bh][d][t] bf16 ; invn: [bh][t] f32 ; ctx: [m][1024] bf16
__global__ __launch_bounds__(256, 2) void k_attn(
    const unsigned short* __restrict__ q, const unsigned short* __restrict__ k,
    const unsigned short* __restrict__ v, const float* __restrict__ invn,
    unsigned short* __restrict__ ctx) {
  __shared__ __align__(16) unsigned short Ks[64 * 64];
  __shared__ __align__(16) unsigned short Vt[64 * 64];   // [dv][s]
  __shared__ __align__(16) unsigned short P[4 * 16 * 64];
  int tid = threadIdx.x, w = tid >> 6, lane = tid & 63;
  int bh = blockIdx.y;
  int tq = gridDim.x - 1 - blockIdx.x;   // heavy blocks first
  int t0 = tq * 64;
  const unsigned short* qb = q + (size_t)bh * Ss * Hd;
  const unsigned short* kb = k + (size_t)bh * Ss * Hd;
  const unsigned short* vb = v + (size_t)bh * Hd * Ss;

  bf16x8 qf[2];
  {
    int trow = t0 + w * 16 + (lane & 15);
#pragma unroll
    for (int ks = 0; ks < 2; ++ks)
      qf[ks] = *(const bf16x8*)(qb + (size_t)trow * Hd + ks * 32 + (lane >> 4) * 8);
  }

  f32x4 acc[4] = {};
  int nkv = tq + 1;
  for (int kv = 0; kv < nkv; ++kv) {
    int s0 = kv * 64;
#pragma unroll
    for (int i = 0; i < 2; ++i) {
      int lin = i * 2048 + w * 512 + lane * 8;
      int r = lin >> 6, c = lin & 63;
      gload_lds16(kb + (size_t)(s0 + r) * Hd + c, Ks + i * 2048 + w * 512);
    }
#pragma unroll
    for (int i = 0; i < 2; ++i) {
      int lin = i * 2048 + w * 512 + lane * 8;
      int r = lin >> 6, c = lin & 63;
      gload_lds16(vb + (size_t)r * Ss + s0 + c, Vt + i * 2048 + w * 512);
    }
    __syncthreads();

    f32x4 sacc[4] = {};
#pragma unroll
    for (int nt = 0; nt < 4; ++nt)
#pragma unroll
      for (int ks = 0; ks < 2; ++ks) {
        bf16x8 kf = *(const bf16x8*)(Ks + (nt * 16 + (lane & 15)) * 64 + ks * 32 + (lane >> 4) * 8);
        sacc[nt] = __builtin_amdgcn_mfma_f32_16x16x32_bf16(qf[ks], kf, sacc[nt], 0, 0, 0);
      }

    // mask + convert to bf16 P (per-wave region)
#pragma unroll
    for (int nt = 0; nt < 4; ++nt)
#pragma unroll
      for (int r = 0; r < 4; ++r) {
        int t = t0 + w * 16 + (lane >> 4) * 4 + r;
        int s = s0 + nt * 16 + (lane & 15);
        float vv = (s <= t) ? sacc[nt][r] : 0.f;
        P[w * 1024 + ((lane >> 4) * 4 + r) * 64 + nt * 16 + (lane & 15)] = f2bf(vv);
      }
    __syncthreads();

#pragma unroll
    for (int dt = 0; dt < 4; ++dt)
#pragma unroll
      for (int ks = 0; ks < 2; ++ks) {
        bf16x8 pf = *(const bf16x8*)(P + w * 1024 + (lane & 15) * 64 + ks * 32 + (lane >> 4) * 8);
        bf16x8 vf = *(const bf16x8*)(Vt + (dt * 16 + (lane & 15)) * 64 + ks * 32 + (lane >> 4) * 8);
        acc[dt] = __builtin_amdgcn_mfma_f32_16x16x32_bf16(pf, vf, acc[dt], 0, 0, 0);
      }
    __syncthreads();
  }

  int b = bh >> 4, h = bh & 15;
  float sc[4];
#pragma unroll
  for (int r = 0; r < 4; ++r)
    sc[r] = invn[(size_t)bh * Ss + t0 + w * 16 + (lane >> 4) * 4 + r];
#pragma unroll
  for (int dt = 0; dt < 4; ++dt)
#pragma unroll
    for (int r = 0; r < 4; ++r) {
      int t = t0 + w * 16 + (lane >> 4) * 4 + r;
      size_t m = (size_t)b * Ss + t;
      ctx[m * Dm + h * Hd + dt * 16 + (lane & 15)] = f2bf(acc[dt][r] * sc[r]);
    }
}

// ---------- launch ----------
extern "C" void kernel_launch(void* const* d_in, const int* in_sizes, int n_in,
                              void* d_out, int out_size, void* d_ws, size_t ws_size,
                              hipStream_t stream) {
  const float* x   = (const float*)d_in[0];
  const float* Wqk = (const float*)d_in[1];
  const float* bqk = (const float*)d_in[2];
  const float* Wv  = (const float*)d_in[3];
  const float* bv  = (const float*)d_in[4];
  const float* Wn  = (const float*)d_in[5];
  const float* bn  = (const float*)d_in[6];
  const float* Wo  = (const float*)d_in[7];
  const float* bo  = (const float*)d_in[8];

  char* ws = (char*)d_ws;
  size_t off = 0;
  unsigned short* xb   = (unsigned short*)(ws + off); off += (size_t)Mtot * Dm * 2;        // 8 MB
  unsigned short* wqkT = (unsigned short*)(ws + off); off += (size_t)2048 * 1024 * 2;      // 4 MB
  unsigned short* wvT  = (unsigned short*)(ws + off); off += (size_t)1024 * 1024 * 2;      // 2 MB
  unsigned short* woT  = (unsigned short*)(ws + off); off += (size_t)1024 * 1024 * 2;      // 2 MB
  unsigned short* qbuf = (unsigned short*)(ws + off); off += (size_t)Bb * Hh * Ss * Hd * 2; // 8 MB
  unsigned short* kbuf = (unsigned short*)(ws + off); off += (size_t)Bb * Hh * Ss * Hd * 2; // 8 MB
  unsigned short* vbuf = (unsigned short*)(ws + off); off += (size_t)Bb * Hh * Ss * Hd * 2; // 8 MB
  float* invn          = (float*)(ws + off);          off += (size_t)Bb * Hh * Ss * 4;      // 256 KB
  unsigned short* ctx  = xb;  // alias: xb dead after v-projection GEMM

  // 1) converts
  k_convert_x<<<(Mtot * Dm / 4) / 256, 256, 0, stream>>>(x, xb);
  k_transpose_conv<<<dim3(2048 / 32, 1024 / 32), dim3(32, 8), 0, stream>>>(Wqk, wqkT, 1024, 2048);
  k_transpose_conv<<<dim3(1024 / 32, 1024 / 32), dim3(32, 8), 0, stream>>>(Wv, wvT, 1024, 1024);
  k_transpose_conv<<<dim3(1024 / 32, 1024 / 32), dim3(32, 8), 0, stream>>>(Wo, woT, 1024, 1024);

  // 2) n path (pure f32)
  k_n_proj<<<Mtot / 4, 256, 0, stream>>>(x, Wn, bn, invn);

  // 3) projections
  k_gemm_bt<0><<<dim3(2048 / 128, Mtot / 128), 256, 0, stream>>>(xb, wqkT, bqk, qbuf, kbuf, Mtot, 2048, 1024);
  k_gemm_bt<1><<<dim3(1024 / 128, Mtot / 128), 256, 0, stream>>>(xb, wvT, bv, vbuf, nullptr, Mtot, 1024, 1024);

  // 4) attention
  k_attn<<<dim3(Ss / 64, Bb * Hh), 256, 0, stream>>>(qbuf, kbuf, vbuf, invn, ctx);

  // 5) output projection -> f32 d_out
  k_gemm_bt<2><<<dim3(1024 / 128, Mtot / 128), 256, 0, stream>>>(ctx, woT, bo, d_out, nullptr, Mtot, 1024, 1024);
}

// Round 2
// 146.655 us; speedup vs baseline: 1.4147x; 1.4147x over previous
//
#include <hip/hip_runtime.h>
#include <hip/hip_bf16.h>

// ---------- problem constants ----------
constexpr int Bb   = 2;
constexpr int Ss   = 2048;
constexpr int Dm   = 1024;
constexpr int Hh   = 16;
constexpr int Hd   = 64;
constexpr int Mtot = Bb * Ss;      // 4096
constexpr int NCH  = Ss / 64;      // 32 chunks of 64

typedef __bf16 bf16x8 __attribute__((ext_vector_type(8)));
typedef float  f32x4  __attribute__((ext_vector_type(4)));
typedef __attribute__((address_space(1))) unsigned int u32_as1;
typedef __attribute__((address_space(3))) unsigned int u32_as3;

__device__ __forceinline__ void gload_lds16(const void* g, void* l) {
  __builtin_amdgcn_global_load_lds((const u32_as1*)g, (u32_as3*)l, 16, 0, 0);
}

__device__ __forceinline__ unsigned short f2bf(float f) {
  union { float f; unsigned u; } x; x.f = f;
  unsigned r = x.u + 0x7fffu + ((x.u >> 16) & 1u);   // RNE
  return (unsigned short)(r >> 16);
}

// ---------- convert x f32 -> bf16 (row-major [M,K]) ----------
__global__ void k_convert_x(const float* __restrict__ in, unsigned short* __restrict__ out) {
  int i = blockIdx.x * blockDim.x + threadIdx.x;        // i < Mtot*Dm/4
  float4 v = ((const float4*)in)[i];
  ushort4 o;
  o.x = f2bf(v.x); o.y = f2bf(v.y); o.z = f2bf(v.z); o.w = f2bf(v.w);
  ((ushort4*)out)[i] = o;
}

// ---------- transpose-convert W [K,N] f32 -> Wt [N,K] bf16 ----------
__global__ void k_transpose_conv(const float* __restrict__ W, unsigned short* __restrict__ Wt,
                                 int K, int N) {
  __shared__ float t[32][33];
  int n0 = blockIdx.x * 32, k0 = blockIdx.y * 32;
  int tx = threadIdx.x, ty = threadIdx.y;
#pragma unroll
  for (int j = 0; j < 32; j += 8)
    t[ty + j][tx] = W[(size_t)(k0 + ty + j) * N + n0 + tx];
  __syncthreads();
#pragma unroll
  for (int j = 0; j < 32; j += 8)
    Wt[(size_t)(n0 + ty + j) * K + k0 + tx] = f2bf(t[tx][ty + j]);
}

// ---------- n projection: invn[b,h,s] = exp(-(x @ Wn + bn)) , all f32 ----------
__global__ void k_n_proj(const float* __restrict__ x, const float* __restrict__ Wn,
                         const float* __restrict__ bn, float* __restrict__ invn) {
  __shared__ float xl[4][1024];
  int tid = threadIdx.x, w = tid >> 6, lane = tid & 63;
  int row = blockIdx.x * 4 + w;                       // [0, 4096)
  const float4* x4 = (const float4*)(x + (size_t)row * Dm);
#pragma unroll
  for (int j = 0; j < 4; ++j)
    *(float4*)&xl[w][(j * 64 + lane) * 4] = x4[j * 64 + lane];
  __syncthreads();
  const float4* Wn4 = (const float4*)Wn;
  f32x4 sum = {0.f, 0.f, 0.f, 0.f};
#pragma unroll 4
  for (int j = 0; j < 64; ++j) {
    float xv = xl[w][j * 16 + (lane >> 2)];
    float4 wv = Wn4[j * 64 + lane];
    sum[0] += xv * wv.x; sum[1] += xv * wv.y; sum[2] += xv * wv.z; sum[3] += xv * wv.w;
  }
#pragma unroll
  for (int m = 4; m < 64; m <<= 1) {
    sum[0] += __shfl_xor(sum[0], m);
    sum[1] += __shfl_xor(sum[1], m);
    sum[2] += __shfl_xor(sum[2], m);
    sum[3] += __shfl_xor(sum[3], m);
  }
  if (lane < 4) {
    int b = row >> 11, s = row & 2047;
#pragma unroll
    for (int e = 0; e < 4; ++e) {
      int h = lane * 4 + e;
      float nv = sum[e] + bn[h];
      invn[((size_t)(b * Hh + h)) * Ss + s] = expf(-nv);
    }
  }
}

// ---------- GEMM: A[M,K] bf16 row-major  x  BT[N,K] bf16  (+bias), epilogue scatter ----------
// MODE 0: N=2048, out0=q [bh,t,d], out1=k [bh,t,d], out2=kT [bh,d,t]   (bf16)
// MODE 1: N=1024, out0=vT [bh,d,t]                                     (bf16)
// MODE 2: N=1024, out0=final f32 [m,n]
template <int MODE>
__global__ __launch_bounds__(256, 2) void k_gemm_bt(
    const unsigned short* __restrict__ A, const unsigned short* __restrict__ BT,
    const float* __restrict__ bias, void* __restrict__ out0, void* __restrict__ out1,
    void* __restrict__ out2, int M, int N, int K) {
  __shared__ __align__(16) unsigned short As[128 * 64];
  __shared__ __align__(16) unsigned short Bs[128 * 64];
  int tid = threadIdx.x, w = tid >> 6, lane = tid & 63;
  int m0 = blockIdx.y * 128, n0 = blockIdx.x * 128;
  int wm = w >> 1, wn = w & 1;
  f32x4 acc[4][4] = {};

  for (int kt = 0; kt < (K >> 6); ++kt) {
#pragma unroll
    for (int i = 0; i < 4; ++i) {
      int lin = i * 2048 + w * 512 + lane * 8;
      int r = lin >> 6, c = lin & 63;
      gload_lds16(A + (size_t)(m0 + r) * K + kt * 64 + c, As + i * 2048 + w * 512);
    }
#pragma unroll
    for (int i = 0; i < 4; ++i) {
      int lin = i * 2048 + w * 512 + lane * 8;
      int r = lin >> 6, c = lin & 63;
      gload_lds16(BT + (size_t)(n0 + r) * K + kt * 64 + c, Bs + i * 2048 + w * 512);
    }
    __syncthreads();
#pragma unroll
    for (int ks = 0; ks < 2; ++ks) {
      bf16x8 af[4], bfr[4];
#pragma unroll
      for (int mt = 0; mt < 4; ++mt)
        af[mt] = *(const bf16x8*)(As + (wm * 64 + mt * 16 + (lane & 15)) * 64 + ks * 32 + (lane >> 4) * 8);
#pragma unroll
      for (int nt = 0; nt < 4; ++nt)
        bfr[nt] = *(const bf16x8*)(Bs + (wn * 64 + nt * 16 + (lane & 15)) * 64 + ks * 32 + (lane >> 4) * 8);
#pragma unroll
      for (int mt = 0; mt < 4; ++mt)
#pragma unroll
        for (int nt = 0; nt < 4; ++nt)
          acc[mt][nt] = __builtin_amdgcn_mfma_f32_16x16x32_bf16(af[mt], bfr[nt], acc[mt][nt], 0, 0, 0);
    }
    __syncthreads();
  }

#pragma unroll
  for (int mt = 0; mt < 4; ++mt) {
#pragma unroll
    for (int nt = 0; nt < 4; ++nt) {
      int n = n0 + wn * 64 + nt * 16 + (lane & 15);
      float bb = bias[n];
      int tbase = m0 + wm * 64 + mt * 16 + (lane >> 4) * 4;
      if (MODE == 1) {
        int b = tbase >> 11, t = tbase & 2047;
        int h = n >> 6, d = n & 63;
        ushort4 o;
        o.x = f2bf(acc[mt][nt][0] + bb);
        o.y = f2bf(acc[mt][nt][1] + bb);
        o.z = f2bf(acc[mt][nt][2] + bb);
        o.w = f2bf(acc[mt][nt][3] + bb);
        *(ushort4*)((unsigned short*)out0 + ((size_t)(b * Hh + h) * Hd + d) * Ss + t) = o;
      } else if (MODE == 0) {
        int sel = n >> 10, h = (n >> 6) & 15, d = n & 63, b = tbase >> 11, t = tbase & 2047;
        unsigned short* dst = sel ? (unsigned short*)out1 : (unsigned short*)out0;
#pragma unroll
        for (int r = 0; r < 4; ++r)
          dst[(((size_t)(b * Hh + h)) * Ss + t + r) * Hd + d] = f2bf(acc[mt][nt][r] + bb);
        if (sel) {  // also write kT [bh][d][t]
          ushort4 o;
          o.x = f2bf(acc[mt][nt][0] + bb);
          o.y = f2bf(acc[mt][nt][1] + bb);
          o.z = f2bf(acc[mt][nt][2] + bb);
          o.w = f2bf(acc[mt][nt][3] + bb);
          *(ushort4*)((unsigned short*)out2 + ((size_t)(b * Hh + h) * Hd + d) * Ss + t) = o;
        }
      } else {  // MODE 2
#pragma unroll
        for (int r = 0; r < 4; ++r)
          ((float*)out0)[(size_t)(tbase + r) * N + n] = acc[mt][nt][r] + bb;
      }
    }
  }
}

// ---------- pass A: per-head chunked state scan ----------
// S'_j[dv][d] = sum_{s < 64j} v[s][dv] * k[s][d]   (exclusive prefix), bf16 out
// grid (4 dv-slices, 32 bh), 1 wave per block, zero barriers, depth-1 prefetch.
__global__ __launch_bounds__(64) void k_state(
    const unsigned short* __restrict__ vT, const unsigned short* __restrict__ kT,
    unsigned short* __restrict__ Sp) {
  int lane = threadIdx.x;
  int dv0 = blockIdx.x * 16;
  int bh = blockIdx.y;
  const unsigned short* vb = vT + (size_t)bh * Hd * Ss;
  const unsigned short* kb = kT + (size_t)bh * Hd * Ss;
  unsigned short* sp = Sp + (size_t)bh * NCH * 4096;
  f32x4 acc[4] = {};
  bf16x8 afA[2], bfA[4][2], afB[2], bfB[4][2];

#define LOADCH(j, af, bf) do {                                                              \
    int t0_ = (j) * 64;                                                                     \
    _Pragma("unroll") for (int ks = 0; ks < 2; ++ks)                                        \
      af[ks] = *(const bf16x8*)(vb + (size_t)(dv0 + (lane & 15)) * Ss + t0_ + ks * 32 + (lane >> 4) * 8); \
    _Pragma("unroll") for (int nt = 0; nt < 4; ++nt)                                        \
      _Pragma("unroll") for (int ks = 0; ks < 2; ++ks)                                      \
        bf[nt][ks] = *(const bf16x8*)(kb + (size_t)(nt * 16 + (lane & 15)) * Ss + t0_ + ks * 32 + (lane >> 4) * 8); \
  } while (0)

#define STORES(j) do {                                                                      \
    _Pragma("unroll") for (int nt = 0; nt < 4; ++nt)                                        \
      _Pragma("unroll") for (int r = 0; r < 4; ++r)                                         \
        sp[((size_t)(j) * 64 + dv0 + (lane >> 4) * 4 + r) * 64 + nt * 16 + (lane & 15)] = f2bf(acc[nt][r]); \
  } while (0)

#define MFMAS(af, bf) do {                                                                  \
    _Pragma("unroll") for (int nt = 0; nt < 4; ++nt)                                        \
      _Pragma("unroll") for (int ks = 0; ks < 2; ++ks)                                      \
        acc[nt] = __builtin_amdgcn_mfma_f32_16x16x32_bf16(af[ks], bf[nt][ks], acc[nt], 0, 0, 0); \
  } while (0)

  LOADCH(0, afA, bfA);
  for (int jj = 0; jj < NCH / 2; ++jj) {
    int j0 = jj * 2;
    STORES(j0);                          // exclusive prefix: write BEFORE accumulating
    LOADCH(j0 + 1, afB, bfB);
    MFMAS(afA, bfA);
    STORES(j0 + 1);
    if (j0 + 2 < NCH) LOADCH(j0 + 2, afA, bfA);
    MFMAS(afB, bfB);
  }
#undef LOADCH
#undef STORES
#undef MFMAS
}

// ---------- pass B: per-chunk attention  ctx = (Q@S'^T + tril(QK^T)@V) * invn ----------
// grid (32 chunks, 32 bh), 256 threads (4 waves x 16 t-rows). No __syncthreads.
__global__ __launch_bounds__(256, 4) void k_chunk_attn(
    const unsigned short* __restrict__ q, const unsigned short* __restrict__ k,
    const unsigned short* __restrict__ vT, const unsigned short* __restrict__ Sp,
    const float* __restrict__ invn, unsigned short* __restrict__ ctx) {
  __shared__ __align__(16) unsigned short P[4 * 16 * 64];
  int tid = threadIdx.x, w = tid >> 6, lane = tid & 63;
  int j = blockIdx.x, bh = blockIdx.y;
  int t0 = j * 64;
  const unsigned short* qb = q + (size_t)bh * Ss * Hd;
  const unsigned short* kb = k + (size_t)bh * Ss * Hd;
  const unsigned short* vb = vT + (size_t)bh * Hd * Ss;
  const unsigned short* sp = Sp + ((size_t)bh * NCH + j) * 4096;

  // Q fragments (A operand): row = t-local, k = d
  bf16x8 qf[2];
#pragma unroll
  for (int ks = 0; ks < 2; ++ks)
    qf[ks] = *(const bf16x8*)(qb + (size_t)(t0 + w * 16 + (lane & 15)) * Hd + ks * 32 + (lane >> 4) * 8);

  // Q @ S'  (BT operand = S'[dv][d], d-contiguous)
  f32x4 acc[4] = {};
#pragma unroll
  for (int nt = 0; nt < 4; ++nt)
#pragma unroll
    for (int ks = 0; ks < 2; ++ks) {
      bf16x8 sf = *(const bf16x8*)(sp + (nt * 16 + (lane & 15)) * 64 + ks * 32 + (lane >> 4) * 8);
      acc[nt] = __builtin_amdgcn_mfma_f32_16x16x32_bf16(qf[ks], sf, acc[nt], 0, 0, 0);
    }

  // QK^T within chunk (BT operand = K[s][d])
  f32x4 sacc[4] = {};
#pragma unroll
  for (int nt = 0; nt < 4; ++nt)
#pragma unroll
    for (int ks = 0; ks < 2; ++ks) {
      bf16x8 kf = *(const bf16x8*)(kb + (size_t)(t0 + nt * 16 + (lane & 15)) * Hd + ks * 32 + (lane >> 4) * 8);
      sacc[nt] = __builtin_amdgcn_mfma_f32_16x16x32_bf16(qf[ks], kf, sacc[nt], 0, 0, 0);
    }

  // mask + bf16 P -> LDS (wave-local region, XOR-swizzled rows to avoid 128B-stride conflicts)
#pragma unroll
  for (int nt = 0; nt < 4; ++nt)
#pragma unroll
    for (int r = 0; r < 4; ++r) {
      int row = (lane >> 4) * 4 + r;          // t-local within wave block
      int s_local = nt * 16 + (lane & 15);
      float vv = (s_local <= w * 16 + row) ? sacc[nt][r] : 0.f;
      int cb = s_local * 2;
      int byte = w * 2048 + row * 128 + (cb ^ ((row & 7) << 4));
      *(unsigned short*)((char*)P + byte) = f2bf(vv);
    }
  asm volatile("" ::: "memory");  // keep compiler from moving P reads above writes (HW is in-order per wave)

  // P @ V  (A = P[t][s], BT = V^T[dv][s])
  bf16x8 pf[2];
#pragma unroll
  for (int ks = 0; ks < 2; ++ks) {
    int prow = lane & 15;
    int pcb = (ks * 32 + (lane >> 4) * 8) * 2;
    pf[ks] = *(const bf16x8*)((char*)P + w * 2048 + prow * 128 + (pcb ^ ((prow & 7) << 4)));
  }
#pragma unroll
  for (int dt = 0; dt < 4; ++dt)
#pragma unroll
    for (int ks = 0; ks < 2; ++ks) {
      bf16x8 vf = *(const bf16x8*)(vb + (size_t)(dt * 16 + (lane & 15)) * Ss + t0 + ks * 32 + (lane >> 4) * 8);
      acc[dt] = __builtin_amdgcn_mfma_f32_16x16x32_bf16(pf[ks], vf, acc[dt], 0, 0, 0);
    }

  // epilogue: scale by invn, write ctx [m][1024] bf16
  int b = bh >> 4, h = bh & 15;
  float sc[4];
#pragma unroll
  for (int r = 0; r < 4; ++r)
    sc[r] = invn[(size_t)bh * Ss + t0 + w * 16 + (lane >> 4) * 4 + r];
#pragma unroll
  for (int dt = 0; dt < 4; ++dt)
#pragma unroll
    for (int r = 0; r < 4; ++r) {
      int t = t0 + w * 16 + (lane >> 4) * 4 + r;
      size_t m = (size_t)b * Ss + t;
      ctx[m * Dm + h * Hd + dt * 16 + (lane & 15)] = f2bf(acc[dt][r] * sc[r]);
    }
}

// ---------- launch ----------
extern "C" void kernel_launch(void* const* d_in, const int* in_sizes, int n_in,
                              void* d_out, int out_size, void* d_ws, size_t ws_size,
                              hipStream_t stream) {
  const float* x   = (const float*)d_in[0];
  const float* Wqk = (const float*)d_in[1];
  const float* bqk = (const float*)d_in[2];
  const float* Wv  = (const float*)d_in[3];
  const float* bv  = (const float*)d_in[4];
  const float* Wn  = (const float*)d_in[5];
  const float* bn  = (const float*)d_in[6];
  const float* Wo  = (const float*)d_in[7];
  const float* bo  = (const float*)d_in[8];

  char* ws = (char*)d_ws;
  size_t off = 0;
  unsigned short* xb   = (unsigned short*)(ws + off); off += (size_t)Mtot * Dm * 2;         // 8 MB
  unsigned short* wqkT = (unsigned short*)(ws + off); off += (size_t)2048 * 1024 * 2;       // 4 MB
  unsigned short* wvT  = (unsigned short*)(ws + off); off += (size_t)1024 * 1024 * 2;       // 2 MB
  unsigned short* woT  = (unsigned short*)(ws + off); off += (size_t)1024 * 1024 * 2;       // 2 MB
  unsigned short* qbuf = (unsigned short*)(ws + off); off += (size_t)Bb * Hh * Ss * Hd * 2; // 8 MB
  unsigned short* kbuf = (unsigned short*)(ws + off); off += (size_t)Bb * Hh * Ss * Hd * 2; // 8 MB
  unsigned short* ktbuf= (unsigned short*)(ws + off); off += (size_t)Bb * Hh * Ss * Hd * 2; // 8 MB
  unsigned short* vbuf = (unsigned short*)(ws + off); off += (size_t)Bb * Hh * Ss * Hd * 2; // 8 MB
  float* invn          = (float*)(ws + off);          off += (size_t)Bb * Hh * Ss * 4;      // 256 KB
  unsigned short* Sp   = (unsigned short*)(ws + off); off += (size_t)Bb * Hh * NCH * 4096 * 2; // 8 MB
  unsigned short* ctx  = xb;  // alias: xb dead after v-projection GEMM

  // 1) converts
  k_convert_x<<<(Mtot * Dm / 4) / 256, 256, 0, stream>>>(x, xb);
  k_transpose_conv<<<dim3(2048 / 32, 1024 / 32), dim3(32, 8), 0, stream>>>(Wqk, wqkT, 1024, 2048);
  k_transpose_conv<<<dim3(1024 / 32, 1024 / 32), dim3(32, 8), 0, stream>>>(Wv, wvT, 1024, 1024);
  k_transpose_conv<<<dim3(1024 / 32, 1024 / 32), dim3(32, 8), 0, stream>>>(Wo, woT, 1024, 1024);

  // 2) n path (pure f32)
  k_n_proj<<<Mtot / 4, 256, 0, stream>>>(x, Wn, bn, invn);

  // 3) projections
  k_gemm_bt<0><<<dim3(2048 / 128, Mtot / 128), 256, 0, stream>>>(xb, wqkT, bqk, qbuf, kbuf, ktbuf, Mtot, 2048, 1024);
  k_gemm_bt<1><<<dim3(1024 / 128, Mtot / 128), 256, 0, stream>>>(xb, wvT, bv, vbuf, nullptr, nullptr, Mtot, 1024, 1024);

  // 4) attention = state scan + per-chunk
  k_state<<<dim3(4, Bb * Hh), 64, 0, stream>>>(vbuf, ktbuf, Sp);
  k_chunk_attn<<<dim3(NCH, Bb * Hh), 256, 0, stream>>>(qbuf, kbuf, vbuf, Sp, invn, ctx);

  // 5) output projection -> f32 d_out
  k_gemm_bt<2><<<dim3(1024 / 128, Mtot / 128), 256, 0, stream>>>(ctx, woT, bo, d_out, nullptr, nullptr, Mtot, 1024, 1024);
}

// Round 3
// 119.017 us; speedup vs baseline: 1.7432x; 1.2322x over previous
//
#include <hip/hip_runtime.h>
#include <hip/hip_bf16.h>

// ---------- problem constants ----------
constexpr int Bb   = 2;
constexpr int Ss   = 2048;
constexpr int Dm   = 1024;
constexpr int Hh   = 16;
constexpr int Hd   = 64;
constexpr int Mtot = Bb * Ss;      // 4096
constexpr int NCH  = Ss / 64;      // 32 chunks of 64

typedef __bf16 bf16x8 __attribute__((ext_vector_type(8)));
typedef float  f32x4  __attribute__((ext_vector_type(4)));
typedef __attribute__((address_space(1))) unsigned int u32_as1;
typedef __attribute__((address_space(3))) unsigned int u32_as3;

__device__ __forceinline__ void gload_lds16(const void* g, void* l) {
  __builtin_amdgcn_global_load_lds((const u32_as1*)g, (u32_as3*)l, 16, 0, 0);
}

__device__ __forceinline__ unsigned short f2bf(float f) {
  union { float f; unsigned u; } x; x.f = f;
  unsigned r = x.u + 0x7fffu + ((x.u >> 16) & 1u);   // RNE
  return (unsigned short)(r >> 16);
}

__device__ __forceinline__ float bf2f(unsigned short s) {
  union { unsigned u; float f; } x; x.u = ((unsigned)s) << 16;
  return x.f;
}

// ---------- transpose-convert W [K,N] f32 -> Wt [N,K] bf16 ----------
__global__ void k_transpose_conv(const float* __restrict__ W, unsigned short* __restrict__ Wt,
                                 int K, int N) {
  __shared__ float t[32][33];
  int n0 = blockIdx.x * 32, k0 = blockIdx.y * 32;
  int tx = threadIdx.x, ty = threadIdx.y;
#pragma unroll
  for (int j = 0; j < 32; j += 8)
    t[ty + j][tx] = W[(size_t)(k0 + ty + j) * N + n0 + tx];
  __syncthreads();
#pragma unroll
  for (int j = 0; j < 32; j += 8)
    Wt[(size_t)(n0 + ty + j) * K + k0 + tx] = f2bf(t[tx][ty + j]);
}

// ---------- n projection + x->bf16 convert ----------
// invn[b,h,s] = exp(-(x @ Wn + bn)); xb[m][k] = bf16(x)
__global__ void k_n_proj(const float* __restrict__ x, const float* __restrict__ Wn,
                         const float* __restrict__ bn, float* __restrict__ invn,
                         unsigned short* __restrict__ xb) {
  __shared__ float xl[4][1024];
  int tid = threadIdx.x, w = tid >> 6, lane = tid & 63;
  int row = blockIdx.x * 4 + w;                       // [0, 4096)
  const float4* x4 = (const float4*)(x + (size_t)row * Dm);
  ushort4* xb4 = (ushort4*)(xb + (size_t)row * Dm);
#pragma unroll
  for (int j = 0; j < 4; ++j) {
    float4 v = x4[j * 64 + lane];
    *(float4*)&xl[w][(j * 64 + lane) * 4] = v;
    ushort4 o;
    o.x = f2bf(v.x); o.y = f2bf(v.y); o.z = f2bf(v.z); o.w = f2bf(v.w);
    xb4[j * 64 + lane] = o;
  }
  __syncthreads();
  const float4* Wn4 = (const float4*)Wn;
  f32x4 sum = {0.f, 0.f, 0.f, 0.f};
#pragma unroll 4
  for (int j = 0; j < 64; ++j) {
    float xv = xl[w][j * 16 + (lane >> 2)];
    float4 wv = Wn4[j * 64 + lane];
    sum[0] += xv * wv.x; sum[1] += xv * wv.y; sum[2] += xv * wv.z; sum[3] += xv * wv.w;
  }
#pragma unroll
  for (int m = 4; m < 64; m <<= 1) {
    sum[0] += __shfl_xor(sum[0], m);
    sum[1] += __shfl_xor(sum[1], m);
    sum[2] += __shfl_xor(sum[2], m);
    sum[3] += __shfl_xor(sum[3], m);
  }
  if (lane < 4) {
    int b = row >> 11, s = row & 2047;
#pragma unroll
    for (int e = 0; e < 4; ++e) {
      int h = lane * 4 + e;
      float nv = sum[e] + bn[h];
      invn[((size_t)(b * Hh + h)) * Ss + s] = expf(-nv);
    }
  }
}

// ---------- GEMM: A[M,K] bf16 x BT[N,K] bf16 (+bias), epilogue scatter ----------
// MODE 0: N=3072 fused projections: n<1024 -> q [bh,t,d]; 1024<=n<2048 -> k [bh,t,d] + kT [bh,d,t];
//         n>=2048 -> vT [bh,d,t].  bias: bqk[n] for n<2048, bv[n-2048] else.
// MODE 2: N=1024, out0=final f32 [m,n], bias=bo.
template <int MODE>
__global__ __launch_bounds__(256, 2) void k_gemm_bt(
    const unsigned short* __restrict__ A, const unsigned short* __restrict__ BT,
    const float* __restrict__ bias0, const float* __restrict__ bias1,
    void* __restrict__ out0, void* __restrict__ out1, void* __restrict__ out2,
    void* __restrict__ out3, int M, int N, int K) {
  __shared__ __align__(16) unsigned short As[128 * 64];
  __shared__ __align__(16) unsigned short Bs[128 * 64];
  int tid = threadIdx.x, w = tid >> 6, lane = tid & 63;
  int m0 = blockIdx.y * 128, n0 = blockIdx.x * 128;
  int wm = w >> 1, wn = w & 1;
  f32x4 acc[4][4] = {};

  for (int kt = 0; kt < (K >> 6); ++kt) {
#pragma unroll
    for (int i = 0; i < 4; ++i) {
      int lin = i * 2048 + w * 512 + lane * 8;
      int r = lin >> 6, c = lin & 63;
      gload_lds16(A + (size_t)(m0 + r) * K + kt * 64 + c, As + i * 2048 + w * 512);
    }
#pragma unroll
    for (int i = 0; i < 4; ++i) {
      int lin = i * 2048 + w * 512 + lane * 8;
      int r = lin >> 6, c = lin & 63;
      gload_lds16(BT + (size_t)(n0 + r) * K + kt * 64 + c, Bs + i * 2048 + w * 512);
    }
    __syncthreads();
#pragma unroll
    for (int ks = 0; ks < 2; ++ks) {
      bf16x8 af[4], bfr[4];
#pragma unroll
      for (int mt = 0; mt < 4; ++mt)
        af[mt] = *(const bf16x8*)(As + (wm * 64 + mt * 16 + (lane & 15)) * 64 + ks * 32 + (lane >> 4) * 8);
#pragma unroll
      for (int nt = 0; nt < 4; ++nt)
        bfr[nt] = *(const bf16x8*)(Bs + (wn * 64 + nt * 16 + (lane & 15)) * 64 + ks * 32 + (lane >> 4) * 8);
#pragma unroll
      for (int mt = 0; mt < 4; ++mt)
#pragma unroll
        for (int nt = 0; nt < 4; ++nt)
          acc[mt][nt] = __builtin_amdgcn_mfma_f32_16x16x32_bf16(af[mt], bfr[nt], acc[mt][nt], 0, 0, 0);
    }
    __syncthreads();
  }

#pragma unroll
  for (int mt = 0; mt < 4; ++mt) {
#pragma unroll
    for (int nt = 0; nt < 4; ++nt) {
      int n = n0 + wn * 64 + nt * 16 + (lane & 15);
      int tbase = m0 + wm * 64 + mt * 16 + (lane >> 4) * 4;
      if (MODE == 0) {
        int region = n >> 10;                 // uniform across lanes (boundaries % 128 == 0)
        int h = (n >> 6) & 15, d = n & 63;
        int b = tbase >> 11, t = tbase & 2047;
        float bb = (region < 2) ? bias0[n] : bias1[n - 2048];
        if (region == 0) {
          unsigned short* qp = (unsigned short*)out0;
#pragma unroll
          for (int r = 0; r < 4; ++r)
            qp[(((size_t)(b * Hh + h)) * Ss + t + r) * Hd + d] = f2bf(acc[mt][nt][r] + bb);
        } else if (region == 1) {
          unsigned short* kp = (unsigned short*)out1;
#pragma unroll
          for (int r = 0; r < 4; ++r)
            kp[(((size_t)(b * Hh + h)) * Ss + t + r) * Hd + d] = f2bf(acc[mt][nt][r] + bb);
          ushort4 o;
          o.x = f2bf(acc[mt][nt][0] + bb);
          o.y = f2bf(acc[mt][nt][1] + bb);
          o.z = f2bf(acc[mt][nt][2] + bb);
          o.w = f2bf(acc[mt][nt][3] + bb);
          *(ushort4*)((unsigned short*)out2 + ((size_t)(b * Hh + h) * Hd + d) * Ss + t) = o;
        } else {
          ushort4 o;
          o.x = f2bf(acc[mt][nt][0] + bb);
          o.y = f2bf(acc[mt][nt][1] + bb);
          o.z = f2bf(acc[mt][nt][2] + bb);
          o.w = f2bf(acc[mt][nt][3] + bb);
          *(ushort4*)((unsigned short*)out3 + ((size_t)(b * Hh + h) * Hd + d) * Ss + t) = o;
        }
      } else {  // MODE 2
        float bb = bias0[n];
#pragma unroll
        for (int r = 0; r < 4; ++r)
          ((float*)out0)[(size_t)(tbase + r) * N + n] = acc[mt][nt][r] + bb;
      }
    }
  }
}

// ---------- pass A1: per-chunk gram  G_j[dv][d] = sum_{s in chunk j} v[s][dv]*k[s][d] ----------
// grid (NCH, 32 bh), 1 wave. Fully parallel, no barriers.
__global__ __launch_bounds__(64) void k_gram(
    const unsigned short* __restrict__ vT, const unsigned short* __restrict__ kT,
    unsigned short* __restrict__ G) {
  int lane = threadIdx.x;
  int j = blockIdx.x, bh = blockIdx.y;
  int t0 = j * 64;
  const unsigned short* vb = vT + (size_t)bh * Hd * Ss;
  const unsigned short* kb = kT + (size_t)bh * Hd * Ss;
  unsigned short* g = G + ((size_t)bh * NCH + j) * 4096;

  bf16x8 af[4][2], bfr[4][2];
#pragma unroll
  for (int mt = 0; mt < 4; ++mt)
#pragma unroll
    for (int ks = 0; ks < 2; ++ks) {
      af[mt][ks]  = *(const bf16x8*)(vb + (size_t)(mt * 16 + (lane & 15)) * Ss + t0 + ks * 32 + (lane >> 4) * 8);
      bfr[mt][ks] = *(const bf16x8*)(kb + (size_t)(mt * 16 + (lane & 15)) * Ss + t0 + ks * 32 + (lane >> 4) * 8);
    }
  f32x4 acc[4][4] = {};
#pragma unroll
  for (int mt = 0; mt < 4; ++mt)
#pragma unroll
    for (int nt = 0; nt < 4; ++nt)
#pragma unroll
      for (int ks = 0; ks < 2; ++ks)
        acc[mt][nt] = __builtin_amdgcn_mfma_f32_16x16x32_bf16(af[mt][ks], bfr[nt][ks], acc[mt][nt], 0, 0, 0);
#pragma unroll
  for (int mt = 0; mt < 4; ++mt)
#pragma unroll
    for (int nt = 0; nt < 4; ++nt)
#pragma unroll
      for (int r = 0; r < 4; ++r)
        g[(mt * 16 + (lane >> 4) * 4 + r) * 64 + nt * 16 + (lane & 15)] = f2bf(acc[mt][nt][r]);
}

// ---------- pass A2: exclusive prefix over chunks, per element ----------
// Sp[bh][j][e] = sum_{i<j} G[bh][i][e]   (f32 accum, bf16 in/out)
__global__ __launch_bounds__(256) void k_prefix(
    const unsigned short* __restrict__ G, unsigned short* __restrict__ Sp) {
  int gidx = blockIdx.x * 256 + threadIdx.x;   // 32 bh * 4096 elems
  int bh = gidx >> 12, e = gidx & 4095;
  const unsigned short* gp = G + (size_t)bh * NCH * 4096 + e;
  unsigned short* sp = Sp + (size_t)bh * NCH * 4096 + e;
  float acc = 0.f;
#pragma unroll 8
  for (int j = 0; j < NCH; ++j) {
    sp[(size_t)j * 4096] = f2bf(acc);
    acc += bf2f(gp[(size_t)j * 4096]);
  }
}

// ---------- pass B: per-chunk attention  ctx = (Q@S'^T + tril(QK^T)@V) * invn ----------
// grid (32 chunks, 32 bh), 256 threads (4 waves x 16 t-rows). No __syncthreads.
__global__ __launch_bounds__(256, 4) void k_chunk_attn(
    const unsigned short* __restrict__ q, const unsigned short* __restrict__ k,
    const unsigned short* __restrict__ vT, const unsigned short* __restrict__ Sp,
    const float* __restrict__ invn, unsigned short* __restrict__ ctx) {
  __shared__ __align__(16) unsigned short P[4 * 16 * 64];
  int tid = threadIdx.x, w = tid >> 6, lane = tid & 63;
  int j = blockIdx.x, bh = blockIdx.y;
  int t0 = j * 64;
  const unsigned short* qb = q + (size_t)bh * Ss * Hd;
  const unsigned short* kb = k + (size_t)bh * Ss * Hd;
  const unsigned short* vb = vT + (size_t)bh * Hd * Ss;
  const unsigned short* sp = Sp + ((size_t)bh * NCH + j) * 4096;

  bf16x8 qf[2];
#pragma unroll
  for (int ks = 0; ks < 2; ++ks)
    qf[ks] = *(const bf16x8*)(qb + (size_t)(t0 + w * 16 + (lane & 15)) * Hd + ks * 32 + (lane >> 4) * 8);

  // Q @ S'^T  (BT operand = S'[dv][d], d-contiguous)
  f32x4 acc[4] = {};
#pragma unroll
  for (int nt = 0; nt < 4; ++nt)
#pragma unroll
    for (int ks = 0; ks < 2; ++ks) {
      bf16x8 sf = *(const bf16x8*)(sp + (nt * 16 + (lane & 15)) * 64 + ks * 32 + (lane >> 4) * 8);
      acc[nt] = __builtin_amdgcn_mfma_f32_16x16x32_bf16(qf[ks], sf, acc[nt], 0, 0, 0);
    }

  // QK^T within chunk
  f32x4 sacc[4] = {};
#pragma unroll
  for (int nt = 0; nt < 4; ++nt)
#pragma unroll
    for (int ks = 0; ks < 2; ++ks) {
      bf16x8 kf = *(const bf16x8*)(kb + (size_t)(t0 + nt * 16 + (lane & 15)) * Hd + ks * 32 + (lane >> 4) * 8);
      sacc[nt] = __builtin_amdgcn_mfma_f32_16x16x32_bf16(qf[ks], kf, sacc[nt], 0, 0, 0);
    }

  // mask + bf16 P -> LDS (wave-local region, XOR-swizzled rows)
#pragma unroll
  for (int nt = 0; nt < 4; ++nt)
#pragma unroll
    for (int r = 0; r < 4; ++r) {
      int row = (lane >> 4) * 4 + r;
      int s_local = nt * 16 + (lane & 15);
      float vv = (s_local <= w * 16 + row) ? sacc[nt][r] : 0.f;
      int cb = s_local * 2;
      int byte = w * 2048 + row * 128 + (cb ^ ((row & 7) << 4));
      *(unsigned short*)((char*)P + byte) = f2bf(vv);
    }
  asm volatile("" ::: "memory");

  // P @ V
  bf16x8 pf[2];
#pragma unroll
  for (int ks = 0; ks < 2; ++ks) {
    int prow = lane & 15;
    int pcb = (ks * 32 + (lane >> 4) * 8) * 2;
    pf[ks] = *(const bf16x8*)((char*)P + w * 2048 + prow * 128 + (pcb ^ ((prow & 7) << 4)));
  }
#pragma unroll
  for (int dt = 0; dt < 4; ++dt)
#pragma unroll
    for (int ks = 0; ks < 2; ++ks) {
      bf16x8 vf = *(const bf16x8*)(vb + (size_t)(dt * 16 + (lane & 15)) * Ss + t0 + ks * 32 + (lane >> 4) * 8);
      acc[dt] = __builtin_amdgcn_mfma_f32_16x16x32_bf16(pf[ks], vf, acc[dt], 0, 0, 0);
    }

  // epilogue: scale by invn, write ctx [m][1024] bf16
  int b = bh >> 4, h = bh & 15;
  float sc[4];
#pragma unroll
  for (int r = 0; r < 4; ++r)
    sc[r] = invn[(size_t)bh * Ss + t0 + w * 16 + (lane >> 4) * 4 + r];
#pragma unroll
  for (int dt = 0; dt < 4; ++dt)
#pragma unroll
    for (int r = 0; r < 4; ++r) {
      int t = t0 + w * 16 + (lane >> 4) * 4 + r;
      size_t m = (size_t)b * Ss + t;
      ctx[m * Dm + h * Hd + dt * 16 + (lane & 15)] = f2bf(acc[dt][r] * sc[r]);
    }
}

// ---------- launch ----------
extern "C" void kernel_launch(void* const* d_in, const int* in_sizes, int n_in,
                              void* d_out, int out_size, void* d_ws, size_t ws_size,
                              hipStream_t stream) {
  const float* x   = (const float*)d_in[0];
  const float* Wqk = (const float*)d_in[1];
  const float* bqk = (const float*)d_in[2];
  const float* Wv  = (const float*)d_in[3];
  const float* bv  = (const float*)d_in[4];
  const float* Wn  = (const float*)d_in[5];
  const float* bn  = (const float*)d_in[6];
  const float* Wo  = (const float*)d_in[7];
  const float* bo  = (const float*)d_in[8];

  char* ws = (char*)d_ws;
  size_t off = 0;
  unsigned short* xb    = (unsigned short*)(ws + off); off += (size_t)Mtot * Dm * 2;          // 8 MB
  unsigned short* wprojT= (unsigned short*)(ws + off); off += (size_t)3072 * 1024 * 2;        // 6 MB
  unsigned short* woT   = (unsigned short*)(ws + off); off += (size_t)1024 * 1024 * 2;        // 2 MB
  unsigned short* qbuf  = (unsigned short*)(ws + off); off += (size_t)Bb * Hh * Ss * Hd * 2;  // 8 MB
  unsigned short* kbuf  = (unsigned short*)(ws + off); off += (size_t)Bb * Hh * Ss * Hd * 2;  // 8 MB
  unsigned short* ktbuf = (unsigned short*)(ws + off); off += (size_t)Bb * Hh * Ss * Hd * 2;  // 8 MB
  unsigned short* vbuf  = (unsigned short*)(ws + off); off += (size_t)Bb * Hh * Ss * Hd * 2;  // 8 MB
  float* invn           = (float*)(ws + off);          off += (size_t)Bb * Hh * Ss * 4;       // 256 KB
  unsigned short* G     = (unsigned short*)(ws + off); off += (size_t)Bb * Hh * NCH * 4096 * 2; // 8 MB
  unsigned short* Sp    = (unsigned short*)(ws + off); off += (size_t)Bb * Hh * NCH * 4096 * 2; // 8 MB
  unsigned short* ctx   = xb;  // alias: xb dead after fused projection GEMM

  // 1) weight transposes (bf16, [N][K])
  k_transpose_conv<<<dim3(2048 / 32, 1024 / 32), dim3(32, 8), 0, stream>>>(Wqk, wprojT, 1024, 2048);
  k_transpose_conv<<<dim3(1024 / 32, 1024 / 32), dim3(32, 8), 0, stream>>>(Wv, wprojT + (size_t)2048 * 1024, 1024, 1024);
  k_transpose_conv<<<dim3(1024 / 32, 1024 / 32), dim3(32, 8), 0, stream>>>(Wo, woT, 1024, 1024);

  // 2) n path + x conversion
  k_n_proj<<<Mtot / 4, 256, 0, stream>>>(x, Wn, bn, invn, xb);

  // 3) fused q/k/v projections (N = 3072)
  k_gemm_bt<0><<<dim3(3072 / 128, Mtot / 128), 256, 0, stream>>>(
      xb, wprojT, bqk, bv, qbuf, kbuf, ktbuf, vbuf, Mtot, 3072, 1024);

  // 4) attention = parallel gram + parallel prefix + per-chunk
  k_gram<<<dim3(NCH, Bb * Hh), 64, 0, stream>>>(vbuf, ktbuf, G);
  k_prefix<<<(Bb * Hh * 4096) / 256, 256, 0, stream>>>(G, Sp);
  k_chunk_attn<<<dim3(NCH, Bb * Hh), 256, 0, stream>>>(qbuf, kbuf, vbuf, Sp, invn, ctx);

  // 5) output projection -> f32 d_out
  k_gemm_bt<2><<<dim3(1024 / 128, Mtot / 128), 256, 0, stream>>>(
      ctx, woT, bo, nullptr, d_out, nullptr, nullptr, nullptr, Mtot, 1024, 1024);
}